// Round 13
// baseline (207.433 us; speedup 1.0000x reference)
//
#include <hip/hip_runtime.h>
#include <math.h>

#define FEAT_DIM 256
#define NCLS 21
#define TEMP 0.1f
#define NREP 8

typedef float f32x4  __attribute__((ext_vector_type(4)));
typedef float f32x16 __attribute__((ext_vector_type(16)));
typedef int   i32x4  __attribute__((ext_vector_type(4)));
typedef unsigned int u32x4 __attribute__((ext_vector_type(4)));
typedef short bf16x8 __attribute__((ext_vector_type(8)));

__device__ __forceinline__ unsigned int cvt_pk_bf16(float lo, float hi) {
    unsigned int r;
    asm("v_cvt_pk_bf16_f32 %0, %1, %2" : "=v"(r) : "v"(lo), "v"(hi));
    return r;
}

template <int CTRL>
__device__ __forceinline__ float dpp_add(float x) {
    int y = __builtin_amdgcn_update_dpp(
        0, __builtin_bit_cast(int, x), CTRL, 0xF, 0xF, true);
    return x + __builtin_bit_cast(float, y);
}
// sum over each 16-lane group (VALU-only)
__device__ __forceinline__ float sum16(float x) {
    x = dpp_add<0xB1>(x);    // quad_perm xor1
    x = dpp_add<0x4E>(x);    // quad_perm xor2
    x = dpp_add<0x141>(x);   // row_half_mirror (xor4)
    x = dpp_add<0x128>(x);   // row_ror:8 (xor8 within 16)
    return x;
}

// ---------------------------------------------------------------------------
// MFMA scatter-mean, ONE barrier per tile, fully symmetric waves.
//   P1: issue tile t+2 feature loads (depth-2; stay in flight across the raw
//       barrier) + ssq DPP partials -> s_ssp[parity]
//   B1 (lgkm-only fence + raw s_barrier)
//   P2: EVERY wave redundantly computes iv for all 32 px (16 conflict-free
//       ds_read_b32 + rsqrt) -> its own s_ivf[w] copy. Label loads (L1-hot,
//       block working set = 4.6KB) issued first so latency hides under P2.
//   P3: pack B-frags (f32*iv -> bf16), onehot A from label REGS, 2 mfma.
//   P3b: distributed ballot-count: wave w counts classes {w, w+8, w+16}.
// acc[32cls][32ch] = 16 MFMA acc regs for the whole kernel; zero per-element
// LDS flush; no serial sections, no stragglers, no B2.
// ---------------------------------------------------------------------------
__global__ __launch_bounds__(512, 2)
void k_fused(const float* __restrict__ feat, const int* __restrict__ lab,
             float* __restrict__ gsum, float* __restrict__ gcnt, int N) {
    __shared__ float s_ssp[2][8][2][32];   // [parity][wave][chgrp][px]
    __shared__ float s_ivf[8][32];         // per-wave iv copy (wave-private)

    const int tid = threadIdx.x, lane = tid & 63, w = tid >> 6;
    const int half = lane >> 5, ch = lane & 31;   // ch = B-col = A-row(class)
    const int ntile = N / (gridDim.x * 32);       // 36
    const size_t px0 = (size_t)blockIdx.x * ntile * 32;

    const float* fbase = feat + (size_t)(w * 32 + ch) * (size_t)N + px0 + half * 8;

    f32x16 acc = 0.0f;
    float cntacc = 0.f;      // wave w, lane c: count of class c (c % 8 == w)
    float4 VA[4], VB[4], VC3[4];

    // prologue: tiles 0 and 1 in flight
    #pragma unroll
    for (int j = 0; j < 4; ++j)
        VA[j] = *reinterpret_cast<const float4*>(fbase + (j >> 1) * 16 + (j & 1) * 4);
    #pragma unroll
    for (int j = 0; j < 4; ++j)
        VB[j] = *reinterpret_cast<const float4*>(fbase + 32 + (j >> 1) * 16 + (j & 1) * 4);

    auto process = [&](int t, float4 (&VC)[4], float4 (&VN2)[4]) {
        const int par = t & 1;
        // ---- P1: issue tile t+2 loads (stay in flight across raw barrier)
        if (t + 2 < ntile) {
            const float* fn_ = fbase + (size_t)(t + 2) * 32;
            #pragma unroll
            for (int j = 0; j < 4; ++j)
                VN2[j] = *reinterpret_cast<const float4*>(fn_ + (j >> 1) * 16 + (j & 1) * 4);
        }
        // ssq partials: DPP tree over 16-lane channel groups
        #pragma unroll
        for (int c = 0; c < 2; ++c) {
            const float4 v0 = VC[2 * c], v1 = VC[2 * c + 1];
            const float s0 = sum16(v0.x * v0.x);
            const float s1 = sum16(v0.y * v0.y);
            const float s2 = sum16(v0.z * v0.z);
            const float s3 = sum16(v0.w * v0.w);
            const float s4 = sum16(v1.x * v1.x);
            const float s5 = sum16(v1.y * v1.y);
            const float s6 = sum16(v1.z * v1.z);
            const float s7 = sum16(v1.w * v1.w);
            if ((lane & 15) == 0) {            // lanes 0,16,32,48: (half, grp)
                float* b = &s_ssp[par][w][(lane >> 4) & 1][c * 16 + half * 8];
                *reinterpret_cast<f32x4*>(b)     = (f32x4){s0, s1, s2, s3};
                *reinterpret_cast<f32x4*>(b + 4) = (f32x4){s4, s5, s6, s7};
            }
        }
        asm volatile("s_waitcnt lgkmcnt(0)" ::: "memory");
        __builtin_amdgcn_s_barrier();                       // B1 (only barrier)

        // ---- P2: label loads first (L1-hot), then redundant iv (all waves)
        const int* lb = lab + px0 + (size_t)t * 32;
        const i32x4 lf0a = *reinterpret_cast<const i32x4*>(lb + half * 8);
        const i32x4 lf0b = *reinterpret_cast<const i32x4*>(lb + half * 8 + 4);
        const i32x4 lf1a = *reinterpret_cast<const i32x4*>(lb + 16 + half * 8);
        const i32x4 lf1b = *reinterpret_cast<const i32x4*>(lb + 16 + half * 8 + 4);
        const int   labl = lb[ch];                         // lane px = ch

        float ss = 0.f;
        #pragma unroll
        for (int q = 0; q < 8; ++q)
            ss += s_ssp[par][q][0][ch] + s_ssp[par][q][1][ch];
        const float ivl = 1.0f / fmaxf(sqrtf(ss), 1e-12f);
        if (lane < 32) s_ivf[w][lane] = ivl;

        // ---- P3: build fragments, 2 x mfma 32x32x16
        #pragma unroll
        for (int c = 0; c < 2; ++c) {
            const int o = c * 16 + half * 8;
            const i32x4 la = (c == 0) ? lf0a : lf1a;
            const i32x4 lbv = (c == 0) ? lf0b : lf1b;
            const f32x4 iv0 = *reinterpret_cast<const f32x4*>(&s_ivf[w][o]);
            const f32x4 iv1 = *reinterpret_cast<const f32x4*>(&s_ivf[w][o + 4]);
            const float4 v0 = VC[2 * c], v1 = VC[2 * c + 1];
            u32x4 bw, aw;
            bw[0] = cvt_pk_bf16(v0.x * iv0[0], v0.y * iv0[1]);
            bw[1] = cvt_pk_bf16(v0.z * iv0[2], v0.w * iv0[3]);
            bw[2] = cvt_pk_bf16(v1.x * iv1[0], v1.y * iv1[1]);
            bw[3] = cvt_pk_bf16(v1.z * iv1[2], v1.w * iv1[3]);
            aw[0] = (la[0]  == ch ? 0x3F80u : 0u) | (la[1]  == ch ? 0x3F800000u : 0u);
            aw[1] = (la[2]  == ch ? 0x3F80u : 0u) | (la[3]  == ch ? 0x3F800000u : 0u);
            aw[2] = (lbv[0] == ch ? 0x3F80u : 0u) | (lbv[1] == ch ? 0x3F800000u : 0u);
            aw[3] = (lbv[2] == ch ? 0x3F80u : 0u) | (lbv[3] == ch ? 0x3F800000u : 0u);
            acc = __builtin_amdgcn_mfma_f32_32x32x16_bf16(
                __builtin_bit_cast(bf16x8, aw),
                __builtin_bit_cast(bf16x8, bw), acc, 0, 0, 0);
        }

        // ---- P3b: distributed counts (3 ballots per wave, no straggler)
        #pragma unroll
        for (int k = 0; k < 3; ++k) {
            const int c = w + 8 * k;
            if (c < NCLS) {
                const unsigned long long m =
                    __ballot(labl == c) & 0xFFFFFFFFull;   // low 32 = real px
                if (lane == c) cntacc += (float)__popcll(m);
            }
        }
    };

    for (int t = 0; t < ntile; t += 3) {      // 36 % 3 == 0
        process(t,     VA,  VC3);
        process(t + 1, VB,  VA);
        process(t + 2, VC3, VB);
    }

    // ---- merge: acc -> global replica (one atomic per cell per block)
    {
        float* grep = gsum + (size_t)(blockIdx.x & (NREP - 1)) * (NCLS * FEAT_DIM);
        const int dcol = w * 32 + ch;
        #pragma unroll
        for (int r = 0; r < 16; ++r) {
            const int row = (r & 3) + 8 * (r >> 2) + 4 * half;   // class
            if (row < NCLS) atomicAdd(&grep[row * FEAT_DIM + dcol], acc[r]);
        }
    }
    if (lane < NCLS && (lane & 7) == w) atomicAdd(&gcnt[lane], cntacc);
}

// ---------------------------------------------------------------------------
// Finalize: sum replicas -> means -> 21x21 logits -> masked loss.
// ---------------------------------------------------------------------------
__global__ void k_final(const float* __restrict__ gsum,
                        const float* __restrict__ gcnt,
                        const float* __restrict__ proto,
                        float* __restrict__ out) {
    __shared__ float s_mean[NCLS * 257];
    __shared__ float s_icnt[NCLS];
    __shared__ float s_log[NCLS * NCLS];
    __shared__ float s_term[NCLS];

    if (threadIdx.x < NCLS)
        s_icnt[threadIdx.x] = 1.0f / fmaxf(gcnt[threadIdx.x], 1.0f);
    __syncthreads();

    for (int i = threadIdx.x; i < NCLS * FEAT_DIM; i += blockDim.x) {
        float v = 0.f;
        #pragma unroll
        for (int r = 0; r < NREP; ++r) v += gsum[r * NCLS * FEAT_DIM + i];
        const int c = i / FEAT_DIM, d = i - c * FEAT_DIM;
        s_mean[c * 257 + d] = v * s_icnt[c];
    }
    __syncthreads();

    for (int p = threadIdx.x; p < NCLS * NCLS; p += blockDim.x) {
        const int c = p / NCLS, j = p - c * NCLS;
        float acc = 0.f;
        #pragma unroll 8
        for (int d = 0; d < FEAT_DIM; ++d)
            acc += s_mean[c * 257 + d] * proto[j * FEAT_DIM + d];
        s_log[p] = acc / TEMP;
    }
    __syncthreads();

    if (threadIdx.x >= 1 && threadIdx.x < NCLS) {
        const int c = threadIdx.x;
        float m = -INFINITY;
        for (int j = 0; j < NCLS; ++j) m = fmaxf(m, s_log[c * NCLS + j]);
        float den = 0.f;
        for (int j = 1; j < NCLS; ++j) den += expf(s_log[c * NCLS + j] - m);
        s_term[c] = logf(den) - (s_log[c * NCLS + c] - m);
    }
    __syncthreads();

    if (threadIdx.x == 0) {
        float acc = 0.f;
        for (int c = 1; c < NCLS; ++c) acc += s_term[c];
        out[0] = acc / (float)(NCLS - 1);
    }
}

// ---------------------------------------------------------------------------
extern "C" void kernel_launch(void* const* d_in, const int* in_sizes, int n_in,
                              void* d_out, int out_size, void* d_ws, size_t ws_size,
                              hipStream_t stream) {
    const float* feat  = (const float*)d_in[0];
    const float* proto = (const float*)d_in[1];
    const int*   lab   = (const int*)d_in[3];   // d_in[2] "outputs" unused

    const int N = in_sizes[3];                  // 589824 = 512 * 36 * 32

    float* gsum = (float*)d_ws;                 // [NREP][21*256]
    float* gcnt = gsum + NREP * NCLS * FEAT_DIM;

    (void)hipMemsetAsync(gsum, 0,
                         (NREP * NCLS * FEAT_DIM + NCLS) * sizeof(float), stream);

    k_fused<<<512, 512, 0, stream>>>(feat, lab, gsum, gcnt, N);
    k_final<<<1, 256, 0, stream>>>(gsum, gcnt, proto, (float*)d_out);
}

// Round 14
// 169.033 us; speedup vs baseline: 1.2272x; 1.2272x over previous
//
#include <hip/hip_runtime.h>
#include <math.h>

#define FEAT_DIM 256
#define NCLS 21
#define TEMP 0.1f
#define NREP 8

typedef float f32x4  __attribute__((ext_vector_type(4)));
typedef float f32x16 __attribute__((ext_vector_type(16)));
typedef int   i32x4  __attribute__((ext_vector_type(4)));
typedef unsigned int u32x4 __attribute__((ext_vector_type(4)));
typedef short bf16x8 __attribute__((ext_vector_type(8)));

__device__ __forceinline__ unsigned int cvt_pk_bf16(float lo, float hi) {
    unsigned int r;
    asm("v_cvt_pk_bf16_f32 %0, %1, %2" : "=v"(r) : "v"(lo), "v"(hi));
    return r;
}

template <int CTRL>
__device__ __forceinline__ float dpp_add(float x) {
    int y = __builtin_amdgcn_update_dpp(
        0, __builtin_bit_cast(int, x), CTRL, 0xF, 0xF, true);
    return x + __builtin_bit_cast(float, y);
}
// sum over each 16-lane group (VALU-only)
__device__ __forceinline__ float sum16(float x) {
    x = dpp_add<0xB1>(x);    // quad_perm xor1
    x = dpp_add<0x4E>(x);    // quad_perm xor2
    x = dpp_add<0x141>(x);   // row_half_mirror (xor4)
    x = dpp_add<0x128>(x);   // row_ror:8 (xor8 within 16)
    return x;
}

// exchange lane[i+32] of a with lane[i] of b (hardware half-wave swap):
// after: a = {a_lo, b_lo}, b = {a_hi, b_hi}
__device__ __forceinline__ void pl32swap(float& a, float& b) {
    asm volatile("v_permlane32_swap_b32 %0, %1" : "+v"(a), "+v"(b));
}
__device__ __forceinline__ void swap_pair(float4& A, float4& B) {
    pl32swap(A.x, B.x); pl32swap(A.y, B.y);
    pl32swap(A.z, B.z); pl32swap(A.w, B.w);
}

// ---------------------------------------------------------------------------
// MFMA scatter-mean (R12 structure) + SECTOR-COALESCED loads.
// Loads: lane(half,ch) reads row (w*32+ch) at float-offset half*4 — the two
// halves cover a CONTIGUOUS 32B per row per instruction (vs R12's two
// scattered 16B). One v_permlane32_swap_b32 per register pair afterwards
// restores the exact MFMA B-fragment px<->lane mapping:
//   A-load: lo=px[0..3]  hi=px[4..7]   B-load: lo=px[8..11] hi=px[12..15]
//   swap(A,B): A={px0..3|px8..11}? no — A'={A_lo,B_lo} so lane h0 gets
//   [A'(0-3), B'(4-7)] and h1 gets [A'(8-11), B'(12-15)] = R12's layout.
// Everything downstream (ssq DPP partials, s_ssp layout, pack, onehot A,
// 2x mfma 32x32x16, depth-2 prefetch, B1/B2, w0-iv, w1-labels, P3 counts)
// is identical to R12 (166us best).
// ---------------------------------------------------------------------------
__global__ __launch_bounds__(512, 2)
void k_fused(const float* __restrict__ feat, const int* __restrict__ lab,
             float* __restrict__ gsum, float* __restrict__ gcnt, int N) {
    __shared__ float s_ssp[8][2][32];   // [wave][ch-group][px] 16-ch partials
    __shared__ float s_ivf[32];
    __shared__ int   s_lab[32];

    const int tid = threadIdx.x, lane = tid & 63, w = tid >> 6;
    const int half = lane >> 5, ch = lane & 31;   // ch = B-col = A-row(class)
    const int ntile = N / (gridDim.x * 32);       // 36
    const size_t px0 = (size_t)blockIdx.x * ntile * 32;

    // contiguous-sector base: halves are 16B apart within one 32B run
    const float* fbase = feat + (size_t)(w * 32 + ch) * (size_t)N + px0 + half * 4;
    // load offset for j: chunk (j>>1)*16 px, part (j&1)*8 px
    //   j=0: px[c0 0..7], j=1: px[c0 8..15], j=2/3: chunk1

    f32x16 acc = 0.0f;
    float cntacc = 0.f;
    float4 VA[4], VB[4], VC3[4];
    int labA = 0, labB = 0, labC = 0;

    // prologue: tiles 0 and 1 in flight
    if (w == 1) labA = lab[px0 + (lane & 31)];
    #pragma unroll
    for (int j = 0; j < 4; ++j)
        VA[j] = *reinterpret_cast<const float4*>(fbase + (j >> 1) * 16 + (j & 1) * 8);
    if (w == 1) labB = lab[px0 + 32 + (lane & 31)];
    #pragma unroll
    for (int j = 0; j < 4; ++j)
        VB[j] = *reinterpret_cast<const float4*>(fbase + 32 + (j >> 1) * 16 + (j & 1) * 8);

    auto process = [&](int t, float4 (&VC)[4], int labc,
                       float4 (&VN2)[4], int& labn2) {
        // ---- P1a: issue tile t+2 loads (stay in flight across raw barriers)
        if (t + 2 < ntile) {
            if (w == 1) labn2 = lab[px0 + (size_t)(t + 2) * 32 + (lane & 31)];
            const float* fn_ = fbase + (size_t)(t + 2) * 32;
            #pragma unroll
            for (int j = 0; j < 4; ++j)
                VN2[j] = *reinterpret_cast<const float4*>(fn_ + (j >> 1) * 16 + (j & 1) * 8);
        }
        // ---- P1b: restore fragment layout (one swap per chunk pair)
        swap_pair(VC[0], VC[1]);
        swap_pair(VC[2], VC[3]);

        // ssq partials: DPP tree over 16-lane channel groups
        #pragma unroll
        for (int c = 0; c < 2; ++c) {
            const float4 v0 = VC[2 * c], v1 = VC[2 * c + 1];
            const float s0 = sum16(v0.x * v0.x);
            const float s1 = sum16(v0.y * v0.y);
            const float s2 = sum16(v0.z * v0.z);
            const float s3 = sum16(v0.w * v0.w);
            const float s4 = sum16(v1.x * v1.x);
            const float s5 = sum16(v1.y * v1.y);
            const float s6 = sum16(v1.z * v1.z);
            const float s7 = sum16(v1.w * v1.w);
            if ((lane & 15) == 0) {             // lanes 0,16,32,48
                float* b = &s_ssp[w][(lane >> 4) & 1][c * 16 + half * 8];
                *reinterpret_cast<f32x4*>(b)     = (f32x4){s0, s1, s2, s3};
                *reinterpret_cast<f32x4*>(b + 4) = (f32x4){s4, s5, s6, s7};
            }
        }
        asm volatile("s_waitcnt lgkmcnt(0)" ::: "memory");
        __builtin_amdgcn_s_barrier();                       // B1

        // ---- P2 (minimal): w0 -> iv; w1 -> publish labels
        if (w == 0 && lane < 32) {
            float ss = 0.f;
            #pragma unroll
            for (int q = 0; q < 8; ++q)
                ss += s_ssp[q][0][lane] + s_ssp[q][1][lane];
            s_ivf[lane] = 1.0f / fmaxf(sqrtf(ss), 1e-12f);
        }
        if (w == 1 && lane < 32) s_lab[lane] = labc;
        asm volatile("s_waitcnt lgkmcnt(0)" ::: "memory");
        __builtin_amdgcn_s_barrier();                       // B2

        // ---- P3: build fragments, 2 x mfma 32x32x16
        #pragma unroll
        for (int c = 0; c < 2; ++c) {
            const int o = c * 16 + half * 8;
            const i32x4 lb0 = *reinterpret_cast<const i32x4*>(&s_lab[o]);
            const i32x4 lb1 = *reinterpret_cast<const i32x4*>(&s_lab[o + 4]);
            const f32x4 iv0 = *reinterpret_cast<const f32x4*>(&s_ivf[o]);
            const f32x4 iv1 = *reinterpret_cast<const f32x4*>(&s_ivf[o + 4]);
            const float4 v0 = VC[2 * c], v1 = VC[2 * c + 1];
            u32x4 bw, aw;
            bw[0] = cvt_pk_bf16(v0.x * iv0[0], v0.y * iv0[1]);
            bw[1] = cvt_pk_bf16(v0.z * iv0[2], v0.w * iv0[3]);
            bw[2] = cvt_pk_bf16(v1.x * iv1[0], v1.y * iv1[1]);
            bw[3] = cvt_pk_bf16(v1.z * iv1[2], v1.w * iv1[3]);
            aw[0] = (lb0[0] == ch ? 0x3F80u : 0u) | (lb0[1] == ch ? 0x3F800000u : 0u);
            aw[1] = (lb0[2] == ch ? 0x3F80u : 0u) | (lb0[3] == ch ? 0x3F800000u : 0u);
            aw[2] = (lb1[0] == ch ? 0x3F80u : 0u) | (lb1[1] == ch ? 0x3F800000u : 0u);
            aw[3] = (lb1[2] == ch ? 0x3F80u : 0u) | (lb1[3] == ch ? 0x3F800000u : 0u);
            acc = __builtin_amdgcn_mfma_f32_32x32x16_bf16(
                __builtin_bit_cast(bf16x8, aw),
                __builtin_bit_cast(bf16x8, bw), acc, 0, 0, 0);
        }

        // ---- w1 counts here (overlaps other waves' P3/P1)
        if (w == 1) {
            #pragma unroll 1
            for (int c = 0; c < NCLS; ++c) {
                const unsigned long long m =
                    __ballot(labc == c) & 0xFFFFFFFFull;    // low 32 = real px
                if (lane == c) cntacc += (float)__popcll(m);
            }
        }
    };

    for (int t = 0; t < ntile; t += 3) {      // 36 % 3 == 0
        process(t,     VA,  labA, VC3, labC);
        process(t + 1, VB,  labB, VA,  labA);
        process(t + 2, VC3, labC, VB,  labB);
    }

    // ---- merge: acc -> global replica (one atomic per cell per block)
    {
        float* grep = gsum + (size_t)(blockIdx.x & (NREP - 1)) * (NCLS * FEAT_DIM);
        const int dcol = w * 32 + ch;
        #pragma unroll
        for (int r = 0; r < 16; ++r) {
            const int row = (r & 3) + 8 * (r >> 2) + 4 * half;   // class
            if (row < NCLS) atomicAdd(&grep[row * FEAT_DIM + dcol], acc[r]);
        }
    }
    if (w == 1 && lane < NCLS) atomicAdd(&gcnt[lane], cntacc);
}

// ---------------------------------------------------------------------------
// Finalize: sum replicas -> means -> 21x21 logits -> masked loss.
// ---------------------------------------------------------------------------
__global__ void k_final(const float* __restrict__ gsum,
                        const float* __restrict__ gcnt,
                        const float* __restrict__ proto,
                        float* __restrict__ out) {
    __shared__ float s_mean[NCLS * 257];
    __shared__ float s_icnt[NCLS];
    __shared__ float s_log[NCLS * NCLS];
    __shared__ float s_term[NCLS];

    if (threadIdx.x < NCLS)
        s_icnt[threadIdx.x] = 1.0f / fmaxf(gcnt[threadIdx.x], 1.0f);
    __syncthreads();

    for (int i = threadIdx.x; i < NCLS * FEAT_DIM; i += blockDim.x) {
        float v = 0.f;
        #pragma unroll
        for (int r = 0; r < NREP; ++r) v += gsum[r * NCLS * FEAT_DIM + i];
        const int c = i / FEAT_DIM, d = i - c * FEAT_DIM;
        s_mean[c * 257 + d] = v * s_icnt[c];
    }
    __syncthreads();

    for (int p = threadIdx.x; p < NCLS * NCLS; p += blockDim.x) {
        const int c = p / NCLS, j = p - c * NCLS;
        float acc = 0.f;
        #pragma unroll 8
        for (int d = 0; d < FEAT_DIM; ++d)
            acc += s_mean[c * 257 + d] * proto[j * FEAT_DIM + d];
        s_log[p] = acc / TEMP;
    }
    __syncthreads();

    if (threadIdx.x >= 1 && threadIdx.x < NCLS) {
        const int c = threadIdx.x;
        float m = -INFINITY;
        for (int j = 0; j < NCLS; ++j) m = fmaxf(m, s_log[c * NCLS + j]);
        float den = 0.f;
        for (int j = 1; j < NCLS; ++j) den += expf(s_log[c * NCLS + j] - m);
        s_term[c] = logf(den) - (s_log[c * NCLS + c] - m);
    }
    __syncthreads();

    if (threadIdx.x == 0) {
        float acc = 0.f;
        for (int c = 1; c < NCLS; ++c) acc += s_term[c];
        out[0] = acc / (float)(NCLS - 1);
    }
}

// ---------------------------------------------------------------------------
extern "C" void kernel_launch(void* const* d_in, const int* in_sizes, int n_in,
                              void* d_out, int out_size, void* d_ws, size_t ws_size,
                              hipStream_t stream) {
    const float* feat  = (const float*)d_in[0];
    const float* proto = (const float*)d_in[1];
    const int*   lab   = (const int*)d_in[3];   // d_in[2] "outputs" unused

    const int N = in_sizes[3];                  // 589824 = 512 * 36 * 32

    float* gsum = (float*)d_ws;                 // [NREP][21*256]
    float* gcnt = gsum + NREP * NCLS * FEAT_DIM;

    (void)hipMemsetAsync(gsum, 0,
                         (NREP * NCLS * FEAT_DIM + NCLS) * sizeof(float), stream);

    k_fused<<<512, 512, 0, stream>>>(feat, lab, gsum, gcnt, N);
    k_final<<<1, 256, 0, stream>>>(gsum, gcnt, proto, (float*)d_out);
}

// Round 15
// 167.061 us; speedup vs baseline: 1.2417x; 1.0118x over previous
//
#include <hip/hip_runtime.h>
#include <math.h>

#define FEAT_DIM 256
#define NCLS 21
#define TEMP 0.1f
#define NREP 8

typedef float f32x4  __attribute__((ext_vector_type(4)));
typedef float f32x16 __attribute__((ext_vector_type(16)));
typedef int   i32x4  __attribute__((ext_vector_type(4)));
typedef unsigned int u32x4 __attribute__((ext_vector_type(4)));
typedef short bf16x8 __attribute__((ext_vector_type(8)));

__device__ __forceinline__ unsigned int cvt_pk_bf16(float lo, float hi) {
    unsigned int r;
    asm("v_cvt_pk_bf16_f32 %0, %1, %2" : "=v"(r) : "v"(lo), "v"(hi));
    return r;
}

template <int CTRL>
__device__ __forceinline__ float dpp_add(float x) {
    int y = __builtin_amdgcn_update_dpp(
        0, __builtin_bit_cast(int, x), CTRL, 0xF, 0xF, true);
    return x + __builtin_bit_cast(float, y);
}
// sum over each 16-lane group (VALU-only)
__device__ __forceinline__ float sum16(float x) {
    x = dpp_add<0xB1>(x);    // quad_perm xor1
    x = dpp_add<0x4E>(x);    // quad_perm xor2
    x = dpp_add<0x141>(x);   // row_half_mirror (xor4)
    x = dpp_add<0x128>(x);   // row_ror:8 (xor8 within 16)
    return x;
}

// ---------------------------------------------------------------------------
// MFMA scatter-mean with DEPTH-2 prefetch (triple buffer).
// sums[c][d] = sum_px onehot[c][px] * bf16(f[d][px]*iv[px]).
// Wave w owns channels [32w,32w+32); acc[32cls][32ch] = 16 MFMA acc regs for
// the whole kernel (zero per-element LDS flush). Per 32-px tile:
//   P1: issue loads for tile t+2 (dep distance ~2 bodies > 900cy HBM miss
//       latency -> no steady-state stall) + ssq DPP partials -> LDS
//   B1; P2: w0 iv, w1 labels (ballot-count moved OUT of this phase); B2;
//   P3: pack B-frags + onehot A + 2 mfma; w1 ballot-counts here, overlapped.
// Raw s_barrier + lgkm-only fences keep prefetch loads in flight.
// ---------------------------------------------------------------------------
__global__ __launch_bounds__(512, 2)
void k_fused(const float* __restrict__ feat, const int* __restrict__ lab,
             float* __restrict__ gsum, float* __restrict__ gcnt, int N) {
    __shared__ float s_ssp[8][2][32];   // [wave][ch-group][px] 16-ch partials
    __shared__ float s_ivf[32];
    __shared__ int   s_lab[32];

    const int tid = threadIdx.x, lane = tid & 63, w = tid >> 6;
    const int half = lane >> 5, ch = lane & 31;   // ch = B-col = A-row(class)
    const int ntile = N / (gridDim.x * 32);       // 36
    const size_t px0 = (size_t)blockIdx.x * ntile * 32;

    const float* fbase = feat + (size_t)(w * 32 + ch) * (size_t)N + px0 + half * 8;

    f32x16 acc = 0.0f;
    float cntacc = 0.f;
    float4 VA[4], VB[4], VC3[4];
    int labA = 0, labB = 0, labC = 0;

    // prologue: tiles 0 and 1 in flight
    if (w == 1) labA = lab[px0 + (lane & 31)];
    #pragma unroll
    for (int j = 0; j < 4; ++j)
        VA[j] = *reinterpret_cast<const float4*>(fbase + (j >> 1) * 16 + (j & 1) * 4);
    if (w == 1) labB = lab[px0 + 32 + (lane & 31)];
    #pragma unroll
    for (int j = 0; j < 4; ++j)
        VB[j] = *reinterpret_cast<const float4*>(fbase + 32 + (j >> 1) * 16 + (j & 1) * 4);

    auto process = [&](int t, float4 (&VC)[4], int labc,
                       float4 (&VN2)[4], int& labn2) {
        // ---- P1: issue tile t+2 loads (stay in flight across raw barriers)
        if (t + 2 < ntile) {
            if (w == 1) labn2 = lab[px0 + (size_t)(t + 2) * 32 + (lane & 31)];
            const float* fn_ = fbase + (size_t)(t + 2) * 32;
            #pragma unroll
            for (int j = 0; j < 4; ++j)
                VN2[j] = *reinterpret_cast<const float4*>(fn_ + (j >> 1) * 16 + (j & 1) * 4);
        }
        // ssq partials: DPP tree over 16-lane channel groups
        #pragma unroll
        for (int c = 0; c < 2; ++c) {
            const float4 v0 = VC[2 * c], v1 = VC[2 * c + 1];
            const float s0 = sum16(v0.x * v0.x);
            const float s1 = sum16(v0.y * v0.y);
            const float s2 = sum16(v0.z * v0.z);
            const float s3 = sum16(v0.w * v0.w);
            const float s4 = sum16(v1.x * v1.x);
            const float s5 = sum16(v1.y * v1.y);
            const float s6 = sum16(v1.z * v1.z);
            const float s7 = sum16(v1.w * v1.w);
            if ((lane & 15) == 0) {             // lanes 0,16,32,48
                float* b = &s_ssp[w][(lane >> 4) & 1][c * 16 + half * 8];
                *reinterpret_cast<f32x4*>(b)     = (f32x4){s0, s1, s2, s3};
                *reinterpret_cast<f32x4*>(b + 4) = (f32x4){s4, s5, s6, s7};
            }
        }
        asm volatile("s_waitcnt lgkmcnt(0)" ::: "memory");
        __builtin_amdgcn_s_barrier();                       // B1

        // ---- P2 (kept minimal): w0 -> iv; w1 -> publish labels
        if (w == 0 && lane < 32) {
            float ss = 0.f;
            #pragma unroll
            for (int q = 0; q < 8; ++q)
                ss += s_ssp[q][0][lane] + s_ssp[q][1][lane];
            s_ivf[lane] = 1.0f / fmaxf(sqrtf(ss), 1e-12f);
        }
        if (w == 1 && lane < 32) s_lab[lane] = labc;
        asm volatile("s_waitcnt lgkmcnt(0)" ::: "memory");
        __builtin_amdgcn_s_barrier();                       // B2

        // ---- P3: build fragments, 2 x mfma 32x32x16
        #pragma unroll
        for (int c = 0; c < 2; ++c) {
            const int o = c * 16 + half * 8;
            const i32x4 lb0 = *reinterpret_cast<const i32x4*>(&s_lab[o]);
            const i32x4 lb1 = *reinterpret_cast<const i32x4*>(&s_lab[o + 4]);
            const f32x4 iv0 = *reinterpret_cast<const f32x4*>(&s_ivf[o]);
            const f32x4 iv1 = *reinterpret_cast<const f32x4*>(&s_ivf[o + 4]);
            const float4 v0 = VC[2 * c], v1 = VC[2 * c + 1];
            u32x4 bw, aw;
            bw[0] = cvt_pk_bf16(v0.x * iv0[0], v0.y * iv0[1]);
            bw[1] = cvt_pk_bf16(v0.z * iv0[2], v0.w * iv0[3]);
            bw[2] = cvt_pk_bf16(v1.x * iv1[0], v1.y * iv1[1]);
            bw[3] = cvt_pk_bf16(v1.z * iv1[2], v1.w * iv1[3]);
            aw[0] = (lb0[0] == ch ? 0x3F80u : 0u) | (lb0[1] == ch ? 0x3F800000u : 0u);
            aw[1] = (lb0[2] == ch ? 0x3F80u : 0u) | (lb0[3] == ch ? 0x3F800000u : 0u);
            aw[2] = (lb1[0] == ch ? 0x3F80u : 0u) | (lb1[1] == ch ? 0x3F800000u : 0u);
            aw[3] = (lb1[2] == ch ? 0x3F80u : 0u) | (lb1[3] == ch ? 0x3F800000u : 0u);
            acc = __builtin_amdgcn_mfma_f32_32x32x16_bf16(
                __builtin_bit_cast(bf16x8, aw),
                __builtin_bit_cast(bf16x8, bw), acc, 0, 0, 0);
        }

        // ---- w1 counts here (overlaps other waves' P3/P1; no barrier waits)
        if (w == 1) {
            #pragma unroll 1
            for (int c = 0; c < NCLS; ++c) {
                const unsigned long long m =
                    __ballot(labc == c) & 0xFFFFFFFFull;    // low 32 = real px
                if (lane == c) cntacc += (float)__popcll(m);
            }
        }
    };

    for (int t = 0; t < ntile; t += 3) {      // 36 % 3 == 0
        process(t,     VA,  labA, VC3, labC);
        process(t + 1, VB,  labB, VA,  labA);
        process(t + 2, VC3, labC, VB,  labB);
    }

    // ---- merge: acc -> global replica (one atomic per cell per block)
    {
        float* grep = gsum + (size_t)(blockIdx.x & (NREP - 1)) * (NCLS * FEAT_DIM);
        const int dcol = w * 32 + ch;
        #pragma unroll
        for (int r = 0; r < 16; ++r) {
            const int row = (r & 3) + 8 * (r >> 2) + 4 * half;   // class
            if (row < NCLS) atomicAdd(&grep[row * FEAT_DIM + dcol], acc[r]);
        }
    }
    if (w == 1 && lane < NCLS) atomicAdd(&gcnt[lane], cntacc);
}

// ---------------------------------------------------------------------------
// Finalize: sum replicas -> means -> 21x21 logits -> masked loss.
// ---------------------------------------------------------------------------
__global__ void k_final(const float* __restrict__ gsum,
                        const float* __restrict__ gcnt,
                        const float* __restrict__ proto,
                        float* __restrict__ out) {
    __shared__ float s_mean[NCLS * 257];
    __shared__ float s_icnt[NCLS];
    __shared__ float s_log[NCLS * NCLS];
    __shared__ float s_term[NCLS];

    if (threadIdx.x < NCLS)
        s_icnt[threadIdx.x] = 1.0f / fmaxf(gcnt[threadIdx.x], 1.0f);
    __syncthreads();

    for (int i = threadIdx.x; i < NCLS * FEAT_DIM; i += blockDim.x) {
        float v = 0.f;
        #pragma unroll
        for (int r = 0; r < NREP; ++r) v += gsum[r * NCLS * FEAT_DIM + i];
        const int c = i / FEAT_DIM, d = i - c * FEAT_DIM;
        s_mean[c * 257 + d] = v * s_icnt[c];
    }
    __syncthreads();

    for (int p = threadIdx.x; p < NCLS * NCLS; p += blockDim.x) {
        const int c = p / NCLS, j = p - c * NCLS;
        float acc = 0.f;
        #pragma unroll 8
        for (int d = 0; d < FEAT_DIM; ++d)
            acc += s_mean[c * 257 + d] * proto[j * FEAT_DIM + d];
        s_log[p] = acc / TEMP;
    }
    __syncthreads();

    if (threadIdx.x >= 1 && threadIdx.x < NCLS) {
        const int c = threadIdx.x;
        float m = -INFINITY;
        for (int j = 0; j < NCLS; ++j) m = fmaxf(m, s_log[c * NCLS + j]);
        float den = 0.f;
        for (int j = 1; j < NCLS; ++j) den += expf(s_log[c * NCLS + j] - m);
        s_term[c] = logf(den) - (s_log[c * NCLS + c] - m);
    }
    __syncthreads();

    if (threadIdx.x == 0) {
        float acc = 0.f;
        for (int c = 1; c < NCLS; ++c) acc += s_term[c];
        out[0] = acc / (float)(NCLS - 1);
    }
}

// ---------------------------------------------------------------------------
extern "C" void kernel_launch(void* const* d_in, const int* in_sizes, int n_in,
                              void* d_out, int out_size, void* d_ws, size_t ws_size,
                              hipStream_t stream) {
    const float* feat  = (const float*)d_in[0];
    const float* proto = (const float*)d_in[1];
    const int*   lab   = (const int*)d_in[3];   // d_in[2] "outputs" unused

    const int N = in_sizes[3];                  // 589824 = 512 * 36 * 32

    float* gsum = (float*)d_ws;                 // [NREP][21*256]
    float* gcnt = gsum + NREP * NCLS * FEAT_DIM;

    (void)hipMemsetAsync(gsum, 0,
                         (NREP * NCLS * FEAT_DIM + NCLS) * sizeof(float), stream);

    k_fused<<<512, 512, 0, stream>>>(feat, lab, gsum, gcnt, N);
    k_final<<<1, 256, 0, stream>>>(gsum, gcnt, proto, (float*)d_out);
}